// Round 13
// baseline (171.267 us; speedup 1.0000x reference)
//
#include <hip/hip_runtime.h>

typedef short s16x8 __attribute__((ext_vector_type(8)));
typedef float f32x4 __attribute__((ext_vector_type(4)));
typedef float f32x16 __attribute__((ext_vector_type(16)));

#define B_ 4
#define C_ 256
#define S_ 4096
#define LOG2E 1.44269504088896f
#define M2 32.0f   // fixed base-2 softmax offset: p = 2^(s' - M2)

#if __has_builtin(__builtin_amdgcn_exp2f)
#define EXP2(x) __builtin_amdgcn_exp2f(x)
#else
#define EXP2(x) __exp2f(x)
#endif

// RNE float -> bf16
__device__ __forceinline__ unsigned short f2b(float f) {
  union { float f; unsigned u; } v; v.f = f;
  unsigned r = v.u + 0x7fffu + ((v.u >> 16) & 1u);
  return (unsigned short)(r >> 16);
}
// cheap round-half-up float -> bf16 (hot loop)
__device__ __forceinline__ unsigned short f2b_fast(float f) {
  union { float f; unsigned u; } v; v.f = f;
  return (unsigned short)((v.u + 0x8000u) >> 16);
}
#define PK2(x, y) ((unsigned)f2b_fast(x) | ((unsigned)f2b_fast(y) << 16))
// 16B LDS load at 8B alignment
__device__ __forceinline__ s16x8 lds_ld8(const unsigned short* p) {
  union { s16x8 v; uint2 u[2]; } r;
  r.u[0] = *(const uint2*)p;
  r.u[1] = *(const uint2*)(p + 4);
  return r.v;
}

// ---- fused QKV projection (MFMA) --------------------------------------------
// ct==0:  rows 0-31 = Q (scaled by LOG2E), rows 32-63 = K (from input)
// ct 1-4: rows = Wv[(ct-1)*64 .. +64) (from original)
// Qb,Kb: [B][S][32] bf16 (n-major).
// Vf (v2, PERMUTED frag layout): [b][jt32(128)][g(8)][s(2)][lane64][e8] bf16,
//   element = V[ch = g*32+(l&31)][ jt32*32 + s*16 + (e&3) + (e>>2)*8 + (l>>5)*4 ]
//   The j-permutation matches the in-register P A-frag order in flash (see below).
__global__ __launch_bounds__(256)
void proj_kernel(const float* __restrict__ x, const float* __restrict__ orig,
                 const float* __restrict__ wq, const float* __restrict__ bq,
                 const float* __restrict__ wk, const float* __restrict__ bk,
                 const float* __restrict__ wv, const float* __restrict__ bv,
                 unsigned short* __restrict__ Qb, unsigned short* __restrict__ Kb,
                 unsigned short* __restrict__ Vf) {
  __shared__ unsigned short Al[64 * 68];
  __shared__ unsigned short Sl[64 * 68];
  const int ct = blockIdx.x >> 6;
  const int jt = blockIdx.x & 63;
  const int n0 = jt * 64;
  const int b  = blockIdx.y;
  const int t  = threadIdx.x;
  const int L = t & 63, w = t >> 6;
  const int mt = w >> 1, nt = w & 1;
  const int g = L >> 5, l32 = L & 31;
  const float* srcb = ((ct == 0) ? x : orig) + (size_t)b * C_ * S_;
  f32x16 acc = (f32x16)0.0f;

  for (int kc = 0; kc < 4; ++kc) {
    const int k0 = kc * 64;
    __syncthreads();
    // stage weights Al[row][c] (64x64)
    #pragma unroll
    for (int rep = 0; rep < 4; ++rep) {
      const int idx = rep * 256 + t;
      const int row = idx >> 4, c4 = (idx & 15) * 4;
      const float* wsrc; int wrow;
      if (ct == 0) {
        if (row < 32) { wsrc = wq; wrow = row; } else { wsrc = wk; wrow = row - 32; }
      } else { wsrc = wv; wrow = (ct - 1) * 64 + row; }
      f32x4 v = *(const f32x4*)(wsrc + (size_t)wrow * 256 + k0 + c4);
      union { unsigned short us[4]; uint2 u2; } pk;
      #pragma unroll
      for (int i = 0; i < 4; ++i) pk.us[i] = f2b(v[i]);
      *(uint2*)&Al[row * 68 + c4] = pk.u2;
    }
    // stage source transposed Sl[n][c], vectorized 8B LDS writes
    {
      const int c4 = (t >> 4) * 4;
      const int n4 = (t & 15) * 4;
      f32x4 v0 = *(const f32x4*)(srcb + (size_t)(k0 + c4 + 0) * S_ + n0 + n4);
      f32x4 v1 = *(const f32x4*)(srcb + (size_t)(k0 + c4 + 1) * S_ + n0 + n4);
      f32x4 v2 = *(const f32x4*)(srcb + (size_t)(k0 + c4 + 2) * S_ + n0 + n4);
      f32x4 v3 = *(const f32x4*)(srcb + (size_t)(k0 + c4 + 3) * S_ + n0 + n4);
      #pragma unroll
      for (int k = 0; k < 4; ++k) {
        union { unsigned short us[4]; uint2 u2; } pk;
        pk.us[0] = f2b(v0[k]); pk.us[1] = f2b(v1[k]);
        pk.us[2] = f2b(v2[k]); pk.us[3] = f2b(v3[k]);
        *(uint2*)&Sl[(n4 + k) * 68 + c4] = pk.u2;
      }
    }
    __syncthreads();
    #pragma unroll
    for (int ks = 0; ks < 4; ++ks) {
      s16x8 af = lds_ld8(&Al[(mt * 32 + l32) * 68 + ks * 16 + g * 8]);
      s16x8 bf = lds_ld8(&Sl[(nt * 32 + l32) * 68 + ks * 16 + g * 8]);
      acc = __builtin_amdgcn_mfma_f32_32x32x16_bf16(af, bf, acc, 0, 0, 0);
    }
  }
  __syncthreads();   // LDS free; reuse Al as repack buffer
  unsigned short* Rl = Al;
  const int n = nt * 32 + l32;
  if (ct == 0) {
    // dump [n][ch]: ch 0..31 = Q, 32..63 = K
    #pragma unroll
    for (int reg = 0; reg < 16; ++reg) {
      const int rr = (reg & 3) + 8 * (reg >> 2) + 4 * g;
      const float val = (mt == 0) ? (acc[reg] + bq[rr]) * LOG2E : acc[reg] + bk[rr];
      Rl[n * 68 + mt * 32 + rr] = f2b(val);
    }
    __syncthreads();
    const int nn = t >> 2, ch0 = (t & 3) * 16;
    s16x8 a = lds_ld8(Rl + nn * 68 + ch0);
    s16x8 c = lds_ld8(Rl + nn * 68 + ch0 + 8);
    unsigned short* dst = (ch0 < 32)
        ? Qb + ((size_t)b * S_ + n0 + nn) * 32 + ch0
        : Kb + ((size_t)b * S_ + n0 + nn) * 32 + (ch0 - 32);
    *(s16x8*)dst = a;
    *(s16x8*)(dst + 8) = c;
  } else {
    const int cg = ct - 1;
    // dump [ch][j]
    #pragma unroll
    for (int reg = 0; reg < 16; ++reg) {
      const int rr = (reg & 3) + 8 * (reg >> 2) + 4 * g;
      const int ch = mt * 32 + rr;
      Rl[ch * 68 + n] = f2b(acc[reg] + bv[cg * 64 + ch]);
    }
    __syncthreads();
    // scatter into Vf2 permuted-frag layout
    #pragma unroll
    for (int k = 0; k < 2; ++k) {
      const int G = t * 2 + k;            // 512 stores of 8 shorts
      const int t2 = G >> 8;              // which jt32 sub-tile of this jt64
      const int gh = (G >> 7) & 1;        // 32-ch half within cg's 64
      const int s  = (G >> 6) & 1;        // 16-j slice within jt32
      const int Lf = G & 63;
      const int hh = Lf >> 5;
      const int ch_l = gh * 32 + (Lf & 31);
      const int jloc = t2 * 32 + s * 16 + hh * 4;
      uint2 q0 = *(const uint2*)&Rl[ch_l * 68 + jloc];       // j: +0..3
      uint2 q1 = *(const uint2*)&Rl[ch_l * 68 + jloc + 8];   // j: +8..11
      unsigned short* dst = Vf + (((size_t)(b * 128 + jt * 2 + t2) * 8)
                                  + cg * 2 + gh) * 1024 + s * 512 + (size_t)Lf * 8;
      *(uint2*)dst = q0;
      *(uint2*)(dst + 4) = q1;
    }
  }
}

// ---- flash attention v3 (measured best: 62.6 us): in-register P -------------
// Grid 256 (b, i0), 512 thr, 8 waves = jq(4) x chh(2); 1 block/CU, 2 waves/SIMD.
// Per step: QK = 2 chained mfma(K,Q) -> lane holds P[i=l&31][16 j on regs];
// exp2 + pack STRAIGHT into PV A-frags (j-permutation baked into Vf2);
// 16 PV mfma into 8 persistent accs. NO LDS, NO barriers in the loop.

#define MFMA32(A, B, C) __builtin_amdgcn_mfma_f32_32x32x16_bf16(A, B, C, 0, 0, 0)

#define LOADV(JT)                                                               \
  {                                                                             \
    const unsigned short* vb = Vf + (((size_t)(b * 128 + (JT)) * 8)             \
                                     + chh * 4) * 1024 + (size_t)L * 8;         \
    v00 = *(const s16x8*)(vb + 0 * 1024);                                       \
    v01 = *(const s16x8*)(vb + 0 * 1024 + 512);                                 \
    v10 = *(const s16x8*)(vb + 1 * 1024);                                       \
    v11 = *(const s16x8*)(vb + 1 * 1024 + 512);                                 \
    v20 = *(const s16x8*)(vb + 2 * 1024);                                       \
    v21 = *(const s16x8*)(vb + 2 * 1024 + 512);                                 \
    v30 = *(const s16x8*)(vb + 3 * 1024);                                       \
    v31 = *(const s16x8*)(vb + 3 * 1024 + 512);                                 \
  }

#define DO_IG(QF0, QF1, A0, A1, A2, A3, LPV)                                    \
  {                                                                             \
    f32x16 p = MFMA32(kc0, QF0, cinit);                                         \
    p = MFMA32(kc1, QF1, p);                                                    \
    const float e0 = EXP2(p[0]),  e1 = EXP2(p[1]),  e2 = EXP2(p[2]),  e3 = EXP2(p[3]);   \
    const float e4 = EXP2(p[4]),  e5 = EXP2(p[5]),  e6 = EXP2(p[6]),  e7 = EXP2(p[7]);   \
    const float e8 = EXP2(p[8]),  e9 = EXP2(p[9]),  e10 = EXP2(p[10]), e11 = EXP2(p[11]); \
    const float e12 = EXP2(p[12]), e13 = EXP2(p[13]), e14 = EXP2(p[14]), e15 = EXP2(p[15]); \
    LPV += (((e0 + e1) + (e2 + e3)) + ((e4 + e5) + (e6 + e7)))                  \
         + (((e8 + e9) + (e10 + e11)) + ((e12 + e13) + (e14 + e15)));           \
    union { unsigned u[4]; s16x8 v; } pa, pb;                                   \
    pa.u[0] = PK2(e0, e1);   pa.u[1] = PK2(e2, e3);                             \
    pa.u[2] = PK2(e4, e5);   pa.u[3] = PK2(e6, e7);                             \
    pb.u[0] = PK2(e8, e9);   pb.u[1] = PK2(e10, e11);                           \
    pb.u[2] = PK2(e12, e13); pb.u[3] = PK2(e14, e15);                           \
    A0 = MFMA32(pa.v, v00, A0);  A0 = MFMA32(pb.v, v01, A0);                    \
    A1 = MFMA32(pa.v, v10, A1);  A1 = MFMA32(pb.v, v11, A1);                    \
    A2 = MFMA32(pa.v, v20, A2);  A2 = MFMA32(pb.v, v21, A2);                    \
    A3 = MFMA32(pa.v, v30, A3);  A3 = MFMA32(pb.v, v31, A3);                    \
  }

#define DUMP_ADD(ACC, IG, CG)                                                   \
  _Pragma("unroll")                                                             \
  for (int r = 0; r < 16; ++r) {                                                \
    const int rr = (r & 3) + 8 * (r >> 2) + 4 * h;                              \
    scr[(IG) * 32 + rr][chh * 128 + (CG) * 32 + l31] += ACC[r];                 \
  }

__global__ __launch_bounds__(512, 2)
void flash_kernel(const unsigned short* __restrict__ Qb,
                  const unsigned short* __restrict__ Kb,
                  const unsigned short* __restrict__ Vf,
                  const float* __restrict__ inp,
                  const float* __restrict__ gamma,
                  float* __restrict__ out) {
  __shared__ float scr[64][260];
  __shared__ float lpart[4][64];
  __shared__ float invl[64];
  const int l  = blockIdx.x;
  const int b  = (l & 7) >> 1;                       // XCD pair per batch
  const int i0 = ((l >> 3) * 2 + (l & 1)) * 64;
  const int t  = threadIdx.x;
  const int L = t & 63, w = t >> 6;
  const int l31 = L & 31, h = L >> 5;
  const int jq = w >> 1, chh = w & 1;
  const float gam = gamma[0];
  const unsigned short* Kbase = Kb + (size_t)b * S_ * 32;

  // zero the reduction scratch (consumed after the loop; ph-0 barrier orders it)
  {
    float* sf = &scr[0][0];
    for (int z = t; z < 64 * 260; z += 512) sf[z] = 0.0f;
  }

  // Q fragments (resident): qf[ig][slice]
  const s16x8 qf00 = *(const s16x8*)(Qb + ((size_t)b * S_ + i0 + l31) * 32 + h * 8);
  const s16x8 qf01 = *(const s16x8*)(Qb + ((size_t)b * S_ + i0 + l31) * 32 + 16 + h * 8);
  const s16x8 qf10 = *(const s16x8*)(Qb + ((size_t)b * S_ + i0 + 32 + l31) * 32 + h * 8);
  const s16x8 qf11 = *(const s16x8*)(Qb + ((size_t)b * S_ + i0 + 32 + l31) * 32 + 16 + h * 8);

  f32x16 a00 = (f32x16)0.0f, a01 = (f32x16)0.0f, a02 = (f32x16)0.0f, a03 = (f32x16)0.0f;
  f32x16 a10 = (f32x16)0.0f, a11 = (f32x16)0.0f, a12 = (f32x16)0.0f, a13 = (f32x16)0.0f;
  float lp0 = 0.f, lp1 = 0.f;
  const f32x16 cinit = (f32x16)(-M2);

  s16x8 kc0, kc1, kn0, kn1;
  s16x8 v00, v01, v10, v11, v20, v21, v30, v31;
  {
    const int jt0 = jq * 32;
    kc0 = *(const s16x8*)(Kbase + (size_t)(jt0 * 32 + l31) * 32 + h * 8);
    kc1 = *(const s16x8*)(Kbase + (size_t)(jt0 * 32 + l31) * 32 + 16 + h * 8);
  }

  for (int st = 0; st < 32; ++st) {
    const int jt = jq * 32 + st;
    LOADV(jt);                                   // issued early, consumed ~20 insts later
    DO_IG(qf00, qf01, a00, a01, a02, a03, lp0);  // ig 0
    {
      const int jn = (jt + 1 < 128) ? jt + 1 : 127;   // clamped tail prefetch
      kn0 = *(const s16x8*)(Kbase + (size_t)(jn * 32 + l31) * 32 + h * 8);
      kn1 = *(const s16x8*)(Kbase + (size_t)(jn * 32 + l31) * 32 + 16 + h * 8);
    }
    DO_IG(qf10, qf11, a10, a11, a12, a13, lp1);  // ig 1 (reuses kc, V)
    kc0 = kn0; kc1 = kn1;
  }

  // ---- row-sum partials: lane holds partial for i = ig*32 + l31
  lp0 += __shfl_xor(lp0, 32, 64);
  lp1 += __shfl_xor(lp1, 32, 64);
  if (chh == 0 && L < 32) {
    lpart[jq][L] = lp0;
    lpart[jq][32 + L] = lp1;
  }
  // ---- O reduction over jq via 4 phases (disjoint ch per chh)
  #pragma unroll 1
  for (int ph = 0; ph < 4; ++ph) {
    __syncthreads();
    if (jq == ph) {
      DUMP_ADD(a00, 0, 0); DUMP_ADD(a01, 0, 1); DUMP_ADD(a02, 0, 2); DUMP_ADD(a03, 0, 3);
      DUMP_ADD(a10, 1, 0); DUMP_ADD(a11, 1, 1); DUMP_ADD(a12, 1, 2); DUMP_ADD(a13, 1, 3);
    }
  }
  __syncthreads();
  if (t < 64) invl[t] = gam / (lpart[0][t] + lpart[1][t] + lpart[2][t] + lpart[3][t]);
  __syncthreads();
  // ---- fused store: thread t -> ch = t>>1, i-half = (t&1)*32
  {
    const int ch = t >> 1;
    const int ih = (t & 1) * 32;
    #pragma unroll
    for (int q = 0; q < 8; ++q) {
      const int il = ih + q * 4;
      const size_t gi = ((size_t)b * C_ + ch) * S_ + i0 + il;
      const f32x4 iv = *(const f32x4*)(inp + gi);
      f32x4 o;
      #pragma unroll
      for (int k = 0; k < 4; ++k)
        o[k] = scr[il + k][ch] * invl[il + k] + iv[k];
      *(f32x4*)(out + gi) = o;
    }
  }
}

// ---- launch -----------------------------------------------------------------
// INSTRUMENTATION ROUND: proj dispatched TWICE (idempotent — identical writes).
// Delta(total) vs the 158.0 us single-proj baseline == proj's (warm) duration.
extern "C" void kernel_launch(void* const* d_in, const int* in_sizes, int n_in,
                              void* d_out, int out_size, void* d_ws, size_t ws_size,
                              hipStream_t stream) {
  const float* inp   = (const float*)d_in[0];
  const float* orig  = (const float*)d_in[1];
  const float* wq    = (const float*)d_in[2];
  const float* bq    = (const float*)d_in[3];
  const float* wk    = (const float*)d_in[4];
  const float* bk    = (const float*)d_in[5];
  const float* wv    = (const float*)d_in[6];
  const float* bv    = (const float*)d_in[7];
  const float* gamma = (const float*)d_in[8];
  float* out = (float*)d_out;

  unsigned short* Qb = (unsigned short*)d_ws;            // [B][S][32] bf16, 1 MB
  unsigned short* Kb = Qb + (size_t)B_ * S_ * 32;        // [B][S][32] bf16, 1 MB
  unsigned short* Vf = Kb + (size_t)B_ * S_ * 32;        // frag-tiled V (v2), 8 MB

  proj_kernel<<<dim3(320, 4), 256, 0, stream>>>(inp, orig, wq, bq, wk, bk, wv, bv, Qb, Kb, Vf);
  proj_kernel<<<dim3(320, 4), 256, 0, stream>>>(inp, orig, wq, bq, wk, bk, wv, bv, Qb, Kb, Vf);
  flash_kernel<<<256, 512, 0, stream>>>(Qb, Kb, Vf, inp, gamma, out);
}

// Round 14
// 154.205 us; speedup vs baseline: 1.1106x; 1.1106x over previous
//
#include <hip/hip_runtime.h>

typedef short s16x8 __attribute__((ext_vector_type(8)));
typedef float f32x4 __attribute__((ext_vector_type(4)));
typedef float f32x16 __attribute__((ext_vector_type(16)));

#define B_ 4
#define C_ 256
#define S_ 4096
#define LOG2E 1.44269504088896f
#define M2 32.0f   // fixed base-2 softmax offset: p = 2^(s' - M2)

#if __has_builtin(__builtin_amdgcn_exp2f)
#define EXP2(x) __builtin_amdgcn_exp2f(x)
#else
#define EXP2(x) __exp2f(x)
#endif

// RNE float -> bf16
__device__ __forceinline__ unsigned short f2b(float f) {
  union { float f; unsigned u; } v; v.f = f;
  unsigned r = v.u + 0x7fffu + ((v.u >> 16) & 1u);
  return (unsigned short)(r >> 16);
}
// cheap round-half-up float -> bf16 (hot loop)
__device__ __forceinline__ unsigned short f2b_fast(float f) {
  union { float f; unsigned u; } v; v.f = f;
  return (unsigned short)((v.u + 0x8000u) >> 16);
}
#define PK2(x, y) ((unsigned)f2b_fast(x) | ((unsigned)f2b_fast(y) << 16))
// 16B LDS load at 8B alignment
__device__ __forceinline__ s16x8 lds_ld8(const unsigned short* p) {
  union { s16x8 v; uint2 u[2]; } r;
  r.u[0] = *(const uint2*)p;
  r.u[1] = *(const uint2*)(p + 4);
  return r.v;
}

// ---- fused QKV projection (MFMA) — unchanged from the 158.0us config --------
// ct==0:  rows 0-31 = Q (scaled by LOG2E), rows 32-63 = K (from input)
// ct 1-4: rows = Wv[(ct-1)*64 .. +64) (from original)
// Qb,Kb: [B][S][32] bf16 (n-major).
// Vf (v2, PERMUTED frag layout): [b][jt32(128)][g(8)][s(2)][lane64][e8] bf16,
//   element = V[ch = g*32+(l&31)][ jt32*32 + s*16 + (e&3) + (e>>2)*8 + (l>>5)*4 ]
__global__ __launch_bounds__(256)
void proj_kernel(const float* __restrict__ x, const float* __restrict__ orig,
                 const float* __restrict__ wq, const float* __restrict__ bq,
                 const float* __restrict__ wk, const float* __restrict__ bk,
                 const float* __restrict__ wv, const float* __restrict__ bv,
                 unsigned short* __restrict__ Qb, unsigned short* __restrict__ Kb,
                 unsigned short* __restrict__ Vf) {
  __shared__ unsigned short Al[64 * 68];
  __shared__ unsigned short Sl[64 * 68];
  const int ct = blockIdx.x >> 6;
  const int jt = blockIdx.x & 63;
  const int n0 = jt * 64;
  const int b  = blockIdx.y;
  const int t  = threadIdx.x;
  const int L = t & 63, w = t >> 6;
  const int mt = w >> 1, nt = w & 1;
  const int g = L >> 5, l32 = L & 31;
  const float* srcb = ((ct == 0) ? x : orig) + (size_t)b * C_ * S_;
  f32x16 acc = (f32x16)0.0f;

  for (int kc = 0; kc < 4; ++kc) {
    const int k0 = kc * 64;
    __syncthreads();
    // stage weights Al[row][c] (64x64)
    #pragma unroll
    for (int rep = 0; rep < 4; ++rep) {
      const int idx = rep * 256 + t;
      const int row = idx >> 4, c4 = (idx & 15) * 4;
      const float* wsrc; int wrow;
      if (ct == 0) {
        if (row < 32) { wsrc = wq; wrow = row; } else { wsrc = wk; wrow = row - 32; }
      } else { wsrc = wv; wrow = (ct - 1) * 64 + row; }
      f32x4 v = *(const f32x4*)(wsrc + (size_t)wrow * 256 + k0 + c4);
      union { unsigned short us[4]; uint2 u2; } pk;
      #pragma unroll
      for (int i = 0; i < 4; ++i) pk.us[i] = f2b(v[i]);
      *(uint2*)&Al[row * 68 + c4] = pk.u2;
    }
    // stage source transposed Sl[n][c], vectorized 8B LDS writes
    {
      const int c4 = (t >> 4) * 4;
      const int n4 = (t & 15) * 4;
      f32x4 v0 = *(const f32x4*)(srcb + (size_t)(k0 + c4 + 0) * S_ + n0 + n4);
      f32x4 v1 = *(const f32x4*)(srcb + (size_t)(k0 + c4 + 1) * S_ + n0 + n4);
      f32x4 v2 = *(const f32x4*)(srcb + (size_t)(k0 + c4 + 2) * S_ + n0 + n4);
      f32x4 v3 = *(const f32x4*)(srcb + (size_t)(k0 + c4 + 3) * S_ + n0 + n4);
      #pragma unroll
      for (int k = 0; k < 4; ++k) {
        union { unsigned short us[4]; uint2 u2; } pk;
        pk.us[0] = f2b(v0[k]); pk.us[1] = f2b(v1[k]);
        pk.us[2] = f2b(v2[k]); pk.us[3] = f2b(v3[k]);
        *(uint2*)&Sl[(n4 + k) * 68 + c4] = pk.u2;
      }
    }
    __syncthreads();
    #pragma unroll
    for (int ks = 0; ks < 4; ++ks) {
      s16x8 af = lds_ld8(&Al[(mt * 32 + l32) * 68 + ks * 16 + g * 8]);
      s16x8 bf = lds_ld8(&Sl[(nt * 32 + l32) * 68 + ks * 16 + g * 8]);
      acc = __builtin_amdgcn_mfma_f32_32x32x16_bf16(af, bf, acc, 0, 0, 0);
    }
  }
  __syncthreads();   // LDS free; reuse Al as repack buffer
  unsigned short* Rl = Al;
  const int n = nt * 32 + l32;
  if (ct == 0) {
    // dump [n][ch]: ch 0..31 = Q, 32..63 = K
    #pragma unroll
    for (int reg = 0; reg < 16; ++reg) {
      const int rr = (reg & 3) + 8 * (reg >> 2) + 4 * g;
      const float val = (mt == 0) ? (acc[reg] + bq[rr]) * LOG2E : acc[reg] + bk[rr];
      Rl[n * 68 + mt * 32 + rr] = f2b(val);
    }
    __syncthreads();
    const int nn = t >> 2, ch0 = (t & 3) * 16;
    s16x8 a = lds_ld8(Rl + nn * 68 + ch0);
    s16x8 c = lds_ld8(Rl + nn * 68 + ch0 + 8);
    unsigned short* dst = (ch0 < 32)
        ? Qb + ((size_t)b * S_ + n0 + nn) * 32 + ch0
        : Kb + ((size_t)b * S_ + n0 + nn) * 32 + (ch0 - 32);
    *(s16x8*)dst = a;
    *(s16x8*)(dst + 8) = c;
  } else {
    const int cg = ct - 1;
    // dump [ch][j]
    #pragma unroll
    for (int reg = 0; reg < 16; ++reg) {
      const int rr = (reg & 3) + 8 * (reg >> 2) + 4 * g;
      const int ch = mt * 32 + rr;
      Rl[ch * 68 + n] = f2b(acc[reg] + bv[cg * 64 + ch]);
    }
    __syncthreads();
    // scatter into Vf2 permuted-frag layout
    #pragma unroll
    for (int k = 0; k < 2; ++k) {
      const int G = t * 2 + k;            // 512 stores of 8 shorts
      const int t2 = G >> 8;              // which jt32 sub-tile of this jt64
      const int gh = (G >> 7) & 1;        // 32-ch half within cg's 64
      const int s  = (G >> 6) & 1;        // 16-j slice within jt32
      const int Lf = G & 63;
      const int hh = Lf >> 5;
      const int ch_l = gh * 32 + (Lf & 31);
      const int jloc = t2 * 32 + s * 16 + hh * 4;
      uint2 q0 = *(const uint2*)&Rl[ch_l * 68 + jloc];       // j: +0..3
      uint2 q1 = *(const uint2*)&Rl[ch_l * 68 + jloc + 8];   // j: +8..11
      unsigned short* dst = Vf + (((size_t)(b * 128 + jt * 2 + t2) * 8)
                                  + cg * 2 + gh) * 1024 + s * 512 + (size_t)Lf * 8;
      *(uint2*)dst = q0;
      *(uint2*)(dst + 4) = q1;
    }
  }
}

// ---- flash attention v6: no-duplication decomposition -----------------------
// Grid 256 (b, i0), 512 thr, 8 waves = ig(2) x jq(4); 1 block/CU, 2 waves/SIMD.
// Each wave: 32 i (its ig), ALL 256 ch (8 accs, 128 AGPR), 1024 j (32 steps).
// vs v3: QK/exp2/pack/lpv duplication across ch-halves ELIMINATED (VALU per
// block halved; MFMA -10%); V read 2x from L2 (~1 GB, well under L2 ceiling).
// Per step: QK 2 chained mfma -> exp2/pack (16) -> PV ch-cols 0-3 (8 mfma)
// -> reload V frags for ch-cols 4-7 -> PV (8 mfma). No LDS/barriers in loop.

#define MFMA32(A, B, C) __builtin_amdgcn_mfma_f32_32x32x16_bf16(A, B, C, 0, 0, 0)

// load 8 V frags: ch-col group half HF (4 cols x 2 j-slices) of tile JT
#define LOADV_H(JT, HF)                                                         \
  {                                                                             \
    const unsigned short* vb = Vf + (((size_t)(b * 128 + (JT)) * 8)             \
                                     + (HF) * 4) * 1024 + (size_t)L * 8;        \
    v0 = *(const s16x8*)(vb + 0 * 1024);                                        \
    v1 = *(const s16x8*)(vb + 0 * 1024 + 512);                                  \
    v2 = *(const s16x8*)(vb + 1 * 1024);                                        \
    v3 = *(const s16x8*)(vb + 1 * 1024 + 512);                                  \
    v4 = *(const s16x8*)(vb + 2 * 1024);                                        \
    v5 = *(const s16x8*)(vb + 2 * 1024 + 512);                                  \
    v6 = *(const s16x8*)(vb + 3 * 1024);                                        \
    v7 = *(const s16x8*)(vb + 3 * 1024 + 512);                                  \
  }

#define PV_H(A0, A1, A2, A3)                                                    \
  A0 = MFMA32(pa.v, v0, A0);  A0 = MFMA32(pb.v, v1, A0);                        \
  A1 = MFMA32(pa.v, v2, A1);  A1 = MFMA32(pb.v, v3, A1);                        \
  A2 = MFMA32(pa.v, v4, A2);  A2 = MFMA32(pb.v, v5, A2);                        \
  A3 = MFMA32(pa.v, v6, A3);  A3 = MFMA32(pb.v, v7, A3);

#define DUMP_ADD(ACC, CG)                                                       \
  _Pragma("unroll")                                                             \
  for (int r = 0; r < 16; ++r) {                                                \
    const int rr = (r & 3) + 8 * (r >> 2) + 4 * h;                              \
    scr[ig * 32 + rr][(CG) * 32 + l31] += ACC[r];                               \
  }

__global__ __launch_bounds__(512, 2)
void flash_kernel(const unsigned short* __restrict__ Qb,
                  const unsigned short* __restrict__ Kb,
                  const unsigned short* __restrict__ Vf,
                  const float* __restrict__ inp,
                  const float* __restrict__ gamma,
                  float* __restrict__ out) {
  __shared__ float scr[64][260];
  __shared__ float lpart[4][64];
  __shared__ float invl[64];
  const int l  = blockIdx.x;
  const int b  = (l & 7) >> 1;                       // XCD pair per batch
  const int i0 = ((l >> 3) * 2 + (l & 1)) * 64;
  const int t  = threadIdx.x;
  const int L = t & 63, w = t >> 6;
  const int l31 = L & 31, h = L >> 5;
  const int ig = w & 1, jq = w >> 1;                 // wave role: i-group, j-stream
  const float gam = gamma[0];
  const unsigned short* Kbase = Kb + (size_t)b * S_ * 32;

  // zero the reduction scratch (consumed after the loop; ph-0 barrier orders it)
  {
    float* sf = &scr[0][0];
    for (int z = t; z < 64 * 260; z += 512) sf[z] = 0.0f;
  }

  // Q fragments (resident, single ig -> 16 VGPR)
  const s16x8 qf0 = *(const s16x8*)(Qb + ((size_t)b * S_ + i0 + ig * 32 + l31) * 32 + h * 8);
  const s16x8 qf1 = *(const s16x8*)(Qb + ((size_t)b * S_ + i0 + ig * 32 + l31) * 32 + 16 + h * 8);

  // 8 accumulators: ch-col c covers ch = c*32 + l31
  f32x16 a0 = (f32x16)0.0f, a1 = (f32x16)0.0f, a2 = (f32x16)0.0f, a3 = (f32x16)0.0f;
  f32x16 a4 = (f32x16)0.0f, a5 = (f32x16)0.0f, a6 = (f32x16)0.0f, a7 = (f32x16)0.0f;
  float lpv = 0.f;
  const f32x16 cinit = (f32x16)(-M2);

  s16x8 kc0, kc1, kn0, kn1;
  s16x8 v0, v1, v2, v3, v4, v5, v6, v7;
  {
    const int jt0 = jq * 32;
    kc0 = *(const s16x8*)(Kbase + (size_t)(jt0 * 32 + l31) * 32 + h * 8);
    kc1 = *(const s16x8*)(Kbase + (size_t)(jt0 * 32 + l31) * 32 + 16 + h * 8);
  }

  for (int st = 0; st < 32; ++st) {
    const int jt = jq * 32 + st;
    LOADV_H(jt, 0);                              // ch-cols 0..3; hidden under QK+exp2
    // ---- QK: lane holds P[i = ig*32+l31][16 j] across regs
    f32x16 p = MFMA32(kc0, qf0, cinit);
    p = MFMA32(kc1, qf1, p);
    {
      const int jn = (st < 31) ? jt + 1 : jt;    // next-step K prefetch
      kn0 = *(const s16x8*)(Kbase + (size_t)(jn * 32 + l31) * 32 + h * 8);
      kn1 = *(const s16x8*)(Kbase + (size_t)(jn * 32 + l31) * 32 + 16 + h * 8);
    }
    // ---- softmax numerator + pack into PV A-frags (j-permutation in Vf2)
    const float e0 = EXP2(p[0]),  e1 = EXP2(p[1]),  e2 = EXP2(p[2]),  e3 = EXP2(p[3]);
    const float e4 = EXP2(p[4]),  e5 = EXP2(p[5]),  e6 = EXP2(p[6]),  e7 = EXP2(p[7]);
    const float e8 = EXP2(p[8]),  e9 = EXP2(p[9]),  e10 = EXP2(p[10]), e11 = EXP2(p[11]);
    const float e12 = EXP2(p[12]), e13 = EXP2(p[13]), e14 = EXP2(p[14]), e15 = EXP2(p[15]);
    lpv += (((e0 + e1) + (e2 + e3)) + ((e4 + e5) + (e6 + e7)))
         + (((e8 + e9) + (e10 + e11)) + ((e12 + e13) + (e14 + e15)));
    union { unsigned u[4]; s16x8 v; } pa, pb;
    pa.u[0] = PK2(e0, e1);   pa.u[1] = PK2(e2, e3);
    pa.u[2] = PK2(e4, e5);   pa.u[3] = PK2(e6, e7);
    pb.u[0] = PK2(e8, e9);   pb.u[1] = PK2(e10, e11);
    pb.u[2] = PK2(e12, e13); pb.u[3] = PK2(e14, e15);
    // ---- PV ch-cols 0..3
    PV_H(a0, a1, a2, a3);
    // ---- reload frags for ch-cols 4..7, then PV them
    LOADV_H(jt, 1);
    PV_H(a4, a5, a6, a7);
    kc0 = kn0; kc1 = kn1;
  }

  // ---- row-sum partials: lane holds partial for i = ig*32 + l31
  lpv += __shfl_xor(lpv, 32, 64);                // combine h halves (j-coverage)
  if (L < 32) lpart[jq][ig * 32 + L] = lpv;      // unique (jq, ig) per wave
  // ---- O reduction over jq via 4 phases (each wave owns rows ig*32..+32)
  #pragma unroll 1
  for (int ph = 0; ph < 4; ++ph) {
    __syncthreads();
    if (jq == ph) {
      DUMP_ADD(a0, 0); DUMP_ADD(a1, 1); DUMP_ADD(a2, 2); DUMP_ADD(a3, 3);
      DUMP_ADD(a4, 4); DUMP_ADD(a5, 5); DUMP_ADD(a6, 6); DUMP_ADD(a7, 7);
    }
  }
  __syncthreads();
  if (t < 64) invl[t] = gam / (lpart[0][t] + lpart[1][t] + lpart[2][t] + lpart[3][t]);
  __syncthreads();
  // ---- fused store: thread t -> ch = t>>1, i-half = (t&1)*32
  {
    const int ch = t >> 1;
    const int ih = (t & 1) * 32;
    #pragma unroll
    for (int q = 0; q < 8; ++q) {
      const int il = ih + q * 4;
      const size_t gi = ((size_t)b * C_ + ch) * S_ + i0 + il;
      const f32x4 iv = *(const f32x4*)(inp + gi);
      f32x4 o;
      #pragma unroll
      for (int k = 0; k < 4; ++k)
        o[k] = scr[il + k][ch] * invl[il + k] + iv[k];
      *(f32x4*)(out + gi) = o;
    }
  }
}

// ---- launch -----------------------------------------------------------------
extern "C" void kernel_launch(void* const* d_in, const int* in_sizes, int n_in,
                              void* d_out, int out_size, void* d_ws, size_t ws_size,
                              hipStream_t stream) {
  const float* inp   = (const float*)d_in[0];
  const float* orig  = (const float*)d_in[1];
  const float* wq    = (const float*)d_in[2];
  const float* bq    = (const float*)d_in[3];
  const float* wk    = (const float*)d_in[4];
  const float* bk    = (const float*)d_in[5];
  const float* wv    = (const float*)d_in[6];
  const float* bv    = (const float*)d_in[7];
  const float* gamma = (const float*)d_in[8];
  float* out = (float*)d_out;

  unsigned short* Qb = (unsigned short*)d_ws;            // [B][S][32] bf16, 1 MB
  unsigned short* Kb = Qb + (size_t)B_ * S_ * 32;        // [B][S][32] bf16, 1 MB
  unsigned short* Vf = Kb + (size_t)B_ * S_ * 32;        // frag-tiled V (v2), 8 MB

  proj_kernel<<<dim3(320, 4), 256, 0, stream>>>(inp, orig, wq, bq, wk, bk, wv, bv, Qb, Kb, Vf);
  flash_kernel<<<256, 512, 0, stream>>>(Qb, Kb, Vf, inp, gamma, out);
}